// Round 4
// baseline (69.337 us; speedup 1.0000x reference)
//
#include <hip/hip_runtime.h>
#include <math.h>

#define BATCH 2
#define CIN 64
#define NSP 4096
#define CK 32
#define CV 64
#define COUT 64
#define EPS 1e-5f
#define S4 0.4204482076268573f   // 32^(-1/4); folded into K (query==key)

#define KB 64                    // keys per chunk

typedef unsigned short ushort_t;
using bf16x8 = __attribute__((ext_vector_type(8))) short;
using f32x4  = __attribute__((ext_vector_type(4))) float;
using float4_t = __attribute__((ext_vector_type(4))) float;

__device__ inline ushort_t f2bf(float f) {
  union { float f; unsigned u; } v; v.f = f;
  unsigned u = v.u;
  return (ushort_t)((u + 0x7FFF + ((u >> 16) & 1)) >> 16);
}

// ---------------------------------------------------------------------------
// Kernel 1: fused transpose + MFMA K/V projections.
//   Loads x 32n x 64c f32 tile -> LDS bf16 (transposed), then
//   K^T[b][n][o] = bf16( BN(key_w @ x) * S4 ),  V[b][o][n] = bf16(value_w@x+b)
// grid = B*(N/32), block 256 (w0,w1: K;  w2,w3: V)
// ---------------------------------------------------------------------------
__global__ __launch_bounds__(256) void kv_kernel(
    const float* __restrict__ x,
    const float* __restrict__ key_w,
    const float* __restrict__ bn_gamma,
    const float* __restrict__ bn_beta,
    const float* __restrict__ bn_mean,
    const float* __restrict__ bn_var,
    const float* __restrict__ value_w,
    const float* __restrict__ value_b,
    ushort_t* __restrict__ KbT,
    ushort_t* __restrict__ Vbf) {
  __shared__ ushort_t XL[32][66];   // [n][c], stride 66 -> conflict-free reads

  int tid = threadIdx.x, wid = tid >> 6, lane = tid & 63;
  int l15 = lane & 15, g = lane >> 4;
  int b  = blockIdx.x / (NSP / 32);
  int n0 = (blockIdx.x % (NSP / 32)) * 32;

  // ---- stage x tile (transposed, bf16) ----
  {
    int n = tid & 31, c8 = tid >> 5;
    const float* xb = x + ((size_t)b * CIN + c8 * 8) * NSP + n0 + n;
#pragma unroll
    for (int j = 0; j < 8; ++j)
      XL[n][c8 * 8 + j] = f2bf(xb[(size_t)j * NSP]);
  }
  __syncthreads();

  if (wid < 2) {
    // ---- K: n-rows n0 + wid*16 ----
    bf16x8 a[2];
#pragma unroll
    for (int kk = 0; kk < 2; ++kk)
      a[kk] = *(const bf16x8*)&XL[wid * 16 + l15][kk * 32 + g * 8];
#pragma unroll
    for (int osub = 0; osub < 2; ++osub) {
      bf16x8 bb[2];
#pragma unroll
      for (int kk = 0; kk < 2; ++kk) {
        const float* wp = key_w + (osub * 16 + l15) * CIN + kk * 32 + g * 8;
#pragma unroll
        for (int j = 0; j < 8; ++j) bb[kk][j] = (short)f2bf(wp[j]);
      }
      f32x4 d; d[0] = 0.f; d[1] = 0.f; d[2] = 0.f; d[3] = 0.f;
      d = __builtin_amdgcn_mfma_f32_16x16x32_bf16(a[0], bb[0], d, 0, 0, 0);
      d = __builtin_amdgcn_mfma_f32_16x16x32_bf16(a[1], bb[1], d, 0, 0, 0);
      int o = osub * 16 + l15;
      float sc  = bn_gamma[o] * rsqrtf(bn_var[o] + EPS);
      float scl = sc * S4;
      float bi  = (bn_beta[o] - bn_mean[o] * sc) * S4;
#pragma unroll
      for (int r = 0; r < 4; ++r) {
        int n = n0 + wid * 16 + 4 * g + r;
        KbT[((size_t)b * NSP + n) * CK + o] = f2bf(d[r] * scl + bi);
      }
    }
  } else {
    // ---- V: o-range (wid-2)*32 .. +32 ----
    bf16x8 bbv[2][2];
#pragma unroll
    for (int nsub = 0; nsub < 2; ++nsub)
#pragma unroll
      for (int kk = 0; kk < 2; ++kk)
        bbv[nsub][kk] = *(const bf16x8*)&XL[nsub * 16 + l15][kk * 32 + g * 8];
#pragma unroll
    for (int os = 0; os < 2; ++os) {
      int osub = (wid - 2) * 2 + os;
      bf16x8 av[2];
#pragma unroll
      for (int kk = 0; kk < 2; ++kk) {
        const float* wp = value_w + (osub * 16 + l15) * CIN + kk * 32 + g * 8;
#pragma unroll
        for (int j = 0; j < 8; ++j) av[kk][j] = (short)f2bf(wp[j]);
      }
#pragma unroll
      for (int nsub = 0; nsub < 2; ++nsub) {
        f32x4 d; d[0] = 0.f; d[1] = 0.f; d[2] = 0.f; d[3] = 0.f;
        d = __builtin_amdgcn_mfma_f32_16x16x32_bf16(av[0], bbv[nsub][0], d, 0, 0, 0);
        d = __builtin_amdgcn_mfma_f32_16x16x32_bf16(av[1], bbv[nsub][1], d, 0, 0, 0);
#pragma unroll
        for (int r = 0; r < 4; ++r) {
          int o = osub * 16 + 4 * g + r;
          int n = n0 + nsub * 16 + l15;
          Vbf[((size_t)b * CV + o) * NSP + n] = f2bf(d[r] + value_b[o]);
        }
      }
    }
  }
}

// ---------------------------------------------------------------------------
// Kernel 2: split-K MFMA flash attention, no max tracking, NO K/V staging:
// fragments read directly from global (K/V total 1.5MB, L2-resident; both
// access patterns are perfectly 64B-line coalesced). No __syncthreads at all.
// grid = (B*N/32, S), block 128 (2 waves x 16 q rows).
// ---------------------------------------------------------------------------
__global__ __launch_bounds__(128) void attn_kernel(
    const ushort_t* __restrict__ KbT,
    const ushort_t* __restrict__ Vbf,
    float* __restrict__ pacc,
    float* __restrict__ pS,
    int segn) {
  __shared__ __align__(16) ushort_t PL[2][16 * 72];  // per-wave P tile

  int tid = threadIdx.x, wid = tid >> 6, lane = tid & 63;
  int l15 = lane & 15, g = lane >> 4;
  int b   = blockIdx.x / (NSP / 32);
  int q0  = (blockIdx.x % (NSP / 32)) * 32;
  int seg0 = blockIdx.y * segn;
  int nts  = segn / KB;

  const ushort_t* Kb = KbT + (size_t)b * NSP * CK;
  const ushort_t* Vb = Vbf + (size_t)b * CV * NSP;

  bf16x8 qf = *(const bf16x8*)&Kb[(size_t)(q0 + wid * 16 + l15) * CK + g * 8];

  f32x4 acc[4];
  float Ssum[4];
#pragma unroll
  for (int cg = 0; cg < 4; ++cg)
#pragma unroll
    for (int r = 0; r < 4; ++r) acc[cg][r] = 0.f;
#pragma unroll
  for (int r = 0; r < 4; ++r) Ssum[r] = 0.f;

  for (int t = 0; t < nts; ++t) {
    int base = seg0 + t * KB;

    // ---- QK^T: kf straight from global (L2) ----
    f32x4 s[4];
#pragma unroll
    for (int kg = 0; kg < 4; ++kg) {
      bf16x8 kf = *(const bf16x8*)&Kb[(size_t)(base + kg * 16 + l15) * CK + g * 8];
      f32x4 z; z[0] = 0.f; z[1] = 0.f; z[2] = 0.f; z[3] = 0.f;
      s[kg] = __builtin_amdgcn_mfma_f32_16x16x32_bf16(qf, kf, z, 0, 0, 0);
    }

    // ---- exp (no max shift), accumulate denom, P -> per-wave LDS ----
#pragma unroll
    for (int r = 0; r < 4; ++r) {
      float ps = 0.f;
#pragma unroll
      for (int kg = 0; kg < 4; ++kg) {
        float p = __expf(s[kg][r]);
        ps += p;
        PL[wid][(4 * g + r) * 72 + kg * 16 + l15] = f2bf(p);
      }
      Ssum[r] += ps;
    }

    // ---- PV: vf straight from global (L2) ----
#pragma unroll
    for (int ks = 0; ks < 2; ++ks) {
      bf16x8 pa = *(const bf16x8*)&PL[wid][l15 * 72 + ks * 32 + g * 8];
#pragma unroll
      for (int cg = 0; cg < 4; ++cg) {
        bf16x8 vf = *(const bf16x8*)&Vb[(size_t)(cg * 16 + l15) * NSP + base + ks * 32 + g * 8];
        acc[cg] = __builtin_amdgcn_mfma_f32_16x16x32_bf16(pa, vf, acc[cg], 0, 0, 0);
      }
    }
  }

  // ---- epilogue: reduce denom over 16-lane groups, write partials ----
#pragma unroll
  for (int r = 0; r < 4; ++r)
#pragma unroll
    for (int msk = 1; msk <= 8; msk <<= 1)
      Ssum[r] += __shfl_xor(Ssum[r], msk, 64);

  float* pb = pacc + ((size_t)(blockIdx.y * BATCH + b) * NSP) * CV;
#pragma unroll
  for (int r = 0; r < 4; ++r) {
    int q = q0 + wid * 16 + 4 * g + r;
#pragma unroll
    for (int cg = 0; cg < 4; ++cg)
      pb[(size_t)q * CV + cg * 16 + l15] = acc[cg][r];
    if (l15 == r) pS[((size_t)blockIdx.y * BATCH + b) * NSP + q] = Ssum[r];
  }
}

// ---------------------------------------------------------------------------
// Kernel 3: merge partials + f32 GEMM + residual.
// grid = B*(N/32), block 256. out = gamma*(W@ctx + Wb) + x
// ---------------------------------------------------------------------------
__global__ __launch_bounds__(256) void proj_kernel(
    const float* __restrict__ pacc,
    const float* __restrict__ pS,
    const float* __restrict__ Ww,
    const float* __restrict__ Wb,
    const float* __restrict__ gamma,
    const float* __restrict__ x,
    float* __restrict__ out,
    int nsplit) {
  __shared__ float Clds[32][68];
  __shared__ float Wlds[64][68];
  __shared__ float Sl[32];

  int tid = threadIdx.x;
  int b   = blockIdx.x / (NSP / 32);
  int n0  = (blockIdx.x % (NSP / 32)) * 32;

#pragma unroll
  for (int i = 0; i < 16; ++i) {           // W: 4096 elems
    int e = tid + i * 256;
    Wlds[e >> 6][e & 63] = Ww[e];
  }
#pragma unroll
  for (int i = 0; i < 8; ++i) {            // merge: 2048 elems
    int e = tid + i * 256;
    int n = e >> 6, v = e & 63;
    float ssum = 0.f;
    for (int s = 0; s < nsplit; ++s)
      ssum += pacc[((size_t)(s * BATCH + b) * NSP + n0 + n) * CV + v];
    Clds[n][v] = ssum;
  }
  if (tid < 32) {
    float ds = 0.f;
    for (int s = 0; s < nsplit; ++s)
      ds += pS[((size_t)s * BATCH + b) * NSP + n0 + tid];
    Sl[tid] = 1.f / ds;
  }
  __syncthreads();

  int n  = tid & 31;
  int og = tid >> 5;                       // 0..7, 8 outputs each
  float invn = Sl[n];
  float acc[8];
#pragma unroll
  for (int j = 0; j < 8; ++j) acc[j] = 0.f;

#pragma unroll
  for (int v4 = 0; v4 < 16; ++v4) {
    float4_t c4 = *(const float4_t*)&Clds[n][v4 * 4];
#pragma unroll
    for (int j = 0; j < 8; ++j) {
      float4_t w4 = *(const float4_t*)&Wlds[og * 8 + j][v4 * 4];
      acc[j] += w4[0] * c4[0] + w4[1] * c4[1] + w4[2] * c4[2] + w4[3] * c4[3];
    }
  }

  float gma = gamma[0];
#pragma unroll
  for (int j = 0; j < 8; ++j) {
    int o = og * 8 + j;
    size_t oi = ((size_t)b * COUT + o) * NSP + n0 + n;
    out[oi] = gma * (acc[j] * invn + Wb[o]) + x[oi];
  }
}

// ---------------------------------------------------------------------------
extern "C" void kernel_launch(void* const* d_in, const int* in_sizes, int n_in,
                              void* d_out, int out_size, void* d_ws, size_t ws_size,
                              hipStream_t stream) {
  const float* x        = (const float*)d_in[0];
  const float* key_w    = (const float*)d_in[1];
  const float* bn_gamma = (const float*)d_in[2];
  const float* bn_beta  = (const float*)d_in[3];
  const float* bn_mean  = (const float*)d_in[4];
  const float* bn_var   = (const float*)d_in[5];
  const float* value_w  = (const float*)d_in[6];
  const float* value_b  = (const float*)d_in[7];
  const float* W_w      = (const float*)d_in[8];
  const float* W_b      = (const float*)d_in[9];
  const float* gamma    = (const float*)d_in[10];
  float* out = (float*)d_out;

  ushort_t* KbT = (ushort_t*)d_ws;                       // [B][N][CK]  bf16
  ushort_t* Vbf = KbT + (size_t)BATCH * NSP * CK;        // [B][CV][N]  bf16
  float*    pacc = (float*)(Vbf + (size_t)BATCH * CV * NSP);
  size_t base_bytes = ((size_t)BATCH * NSP * (CK + CV)) * 2;

  int S = 8;
  while (S > 1 && base_bytes + (size_t)S * BATCH * NSP * (CV + 1) * 4 > ws_size)
    S >>= 1;
  float* pS = pacc + (size_t)S * BATCH * NSP * CV;

  kv_kernel<<<BATCH * (NSP / 32), 256, 0, stream>>>(
      x, key_w, bn_gamma, bn_beta, bn_mean, bn_var, value_w, value_b, KbT, Vbf);
  attn_kernel<<<dim3(BATCH * (NSP / 32), S), 128, 0, stream>>>(
      KbT, Vbf, pacc, pS, NSP / S);
  proj_kernel<<<BATCH * (NSP / 32), 256, 0, stream>>>(
      pacc, pS, W_w, W_b, gamma, x, out, S);
}

// Round 5
// 46.439 us; speedup vs baseline: 1.4931x; 1.4931x over previous
//
#include <hip/hip_runtime.h>
#include <math.h>

#define BATCH 2
#define CIN 64
#define NSP 4096
#define CK 32
#define CV 64
#define COUT 64
#define EPS 1e-5f
#define S4 0.4204482076268573f   // 32^(-1/4); folded into K (query==key)

#define KB 64                    // keys per chunk

typedef unsigned short ushort_t;
using bf16x8 = __attribute__((ext_vector_type(8))) short;
using f32x4  = __attribute__((ext_vector_type(4))) float;
using float4_t = __attribute__((ext_vector_type(4))) float;

__device__ inline ushort_t f2bf(float f) {
  union { float f; unsigned u; } v; v.f = f;
  unsigned u = v.u;
  return (ushort_t)((u + 0x7FFF + ((u >> 16) & 1)) >> 16);
}

// ---------------------------------------------------------------------------
// Kernel 1: fused transpose + MFMA K/V projections.
// grid = B*(N/32), block 256 (w0,w1: K;  w2,w3: V)
// ---------------------------------------------------------------------------
__global__ __launch_bounds__(256) void kv_kernel(
    const float* __restrict__ x,
    const float* __restrict__ key_w,
    const float* __restrict__ bn_gamma,
    const float* __restrict__ bn_beta,
    const float* __restrict__ bn_mean,
    const float* __restrict__ bn_var,
    const float* __restrict__ value_w,
    const float* __restrict__ value_b,
    ushort_t* __restrict__ KbT,
    ushort_t* __restrict__ Vbf) {
  __shared__ ushort_t XL[32][66];   // [n][c], stride 66 -> conflict-free reads

  int tid = threadIdx.x, wid = tid >> 6, lane = tid & 63;
  int l15 = lane & 15, g = lane >> 4;
  int b  = blockIdx.x / (NSP / 32);
  int n0 = (blockIdx.x % (NSP / 32)) * 32;

  // ---- stage x tile (transposed, bf16) ----
  {
    int n = tid & 31, c8 = tid >> 5;
    const float* xb = x + ((size_t)b * CIN + c8 * 8) * NSP + n0 + n;
#pragma unroll
    for (int j = 0; j < 8; ++j)
      XL[n][c8 * 8 + j] = f2bf(xb[(size_t)j * NSP]);
  }
  __syncthreads();

  if (wid < 2) {
    // ---- K: n-rows n0 + wid*16 ----
    bf16x8 a[2];
#pragma unroll
    for (int kk = 0; kk < 2; ++kk)
      a[kk] = *(const bf16x8*)&XL[wid * 16 + l15][kk * 32 + g * 8];
#pragma unroll
    for (int osub = 0; osub < 2; ++osub) {
      bf16x8 bb[2];
#pragma unroll
      for (int kk = 0; kk < 2; ++kk) {
        const float* wp = key_w + (osub * 16 + l15) * CIN + kk * 32 + g * 8;
#pragma unroll
        for (int j = 0; j < 8; ++j) bb[kk][j] = (short)f2bf(wp[j]);
      }
      f32x4 d = {0.f, 0.f, 0.f, 0.f};
      d = __builtin_amdgcn_mfma_f32_16x16x32_bf16(a[0], bb[0], d, 0, 0, 0);
      d = __builtin_amdgcn_mfma_f32_16x16x32_bf16(a[1], bb[1], d, 0, 0, 0);
      int o = osub * 16 + l15;
      float sc  = bn_gamma[o] * rsqrtf(bn_var[o] + EPS);
      float scl = sc * S4;
      float bi  = (bn_beta[o] - bn_mean[o] * sc) * S4;
#pragma unroll
      for (int r = 0; r < 4; ++r) {
        int n = n0 + wid * 16 + 4 * g + r;
        KbT[((size_t)b * NSP + n) * CK + o] = f2bf(d[r] * scl + bi);
      }
    }
  } else {
    // ---- V: o-range (wid-2)*32 .. +32 ----
    bf16x8 bbv[2][2];
#pragma unroll
    for (int nsub = 0; nsub < 2; ++nsub)
#pragma unroll
      for (int kk = 0; kk < 2; ++kk)
        bbv[nsub][kk] = *(const bf16x8*)&XL[nsub * 16 + l15][kk * 32 + g * 8];
#pragma unroll
    for (int os = 0; os < 2; ++os) {
      int osub = (wid - 2) * 2 + os;
      bf16x8 av[2];
#pragma unroll
      for (int kk = 0; kk < 2; ++kk) {
        const float* wp = value_w + (osub * 16 + l15) * CIN + kk * 32 + g * 8;
#pragma unroll
        for (int j = 0; j < 8; ++j) av[kk][j] = (short)f2bf(wp[j]);
      }
#pragma unroll
      for (int nsub = 0; nsub < 2; ++nsub) {
        f32x4 d = {0.f, 0.f, 0.f, 0.f};
        d = __builtin_amdgcn_mfma_f32_16x16x32_bf16(av[0], bbv[nsub][0], d, 0, 0, 0);
        d = __builtin_amdgcn_mfma_f32_16x16x32_bf16(av[1], bbv[nsub][1], d, 0, 0, 0);
#pragma unroll
        for (int r = 0; r < 4; ++r) {
          int o = osub * 16 + 4 * g + r;
          int n = n0 + nsub * 16 + l15;
          Vbf[((size_t)b * CV + o) * NSP + n] = f2bf(d[r] + value_b[o]);
        }
      }
    }
  }
}

// ---------------------------------------------------------------------------
// Kernel 2: split-K MFMA flash attention, 4 waves sharing dbuf'd K/V tiles.
// grid = (B*N/64, S), block 256. 64 q-rows/block, 16 q/wave. No max tracking.
// ---------------------------------------------------------------------------
__global__ __launch_bounds__(256) void attn_kernel(
    const ushort_t* __restrict__ KbT,
    const ushort_t* __restrict__ Vbf,
    float* __restrict__ pacc,
    float* __restrict__ pS,
    int segn) {
  __shared__ __align__(16) ushort_t KT[2][KB * CK];   // 2 x 4 KB
  __shared__ __align__(16) ushort_t VT[2][CV * KB];   // 2 x 8 KB
  __shared__ __align__(16) ushort_t PL[4][16 * 72];   // per-wave P tile

  int tid = threadIdx.x, wid = tid >> 6, lane = tid & 63;
  int l15 = lane & 15, g = lane >> 4;
  int b    = blockIdx.x / (NSP / 64);
  int q0   = (blockIdx.x % (NSP / 64)) * 64;
  int seg0 = blockIdx.y * segn;
  int nts  = segn / KB;

  const ushort_t* Kb = KbT + (size_t)b * NSP * CK;
  const ushort_t* Vb = Vbf + (size_t)b * CV * NSP;

  bf16x8 qf = *(const bf16x8*)&Kb[(size_t)(q0 + wid * 16 + l15) * CK + g * 8];

  f32x4 acc[4];
  float Ssum[4];
#pragma unroll
  for (int cg = 0; cg < 4; ++cg)
#pragma unroll
    for (int r = 0; r < 4; ++r) acc[cg][r] = 0.f;
#pragma unroll
  for (int r = 0; r < 4; ++r) Ssum[r] = 0.f;

  // 4 KB K tile: 256 threads x 16 B = 1 instr/thread
  auto stageK = [&](int nb, int n0) {
    int off = wid * 1024 + lane * 16;
    int key = off >> 6;
    int c16 = (off >> 4) & 3;
    int sw  = c16 ^ ((key >> 1) & 3);
    const ushort_t* src = Kb + (size_t)(n0 + key) * CK + sw * 8;
    ushort_t* dst = &KT[nb][(wid * 1024) >> 1];   // wave-uniform base
    __builtin_amdgcn_global_load_lds(
        (const __attribute__((address_space(1))) unsigned int*)src,
        (__attribute__((address_space(3))) unsigned int*)dst, 16, 0, 0);
  };
  // 8 KB V tile: 2 instrs/thread
  auto stageV = [&](int nb, int n0) {
#pragma unroll
    for (int i = 0; i < 2; ++i) {
      int off = wid * 2048 + i * 1024 + lane * 16;
      int cv  = off >> 7;
      int c16 = (off >> 4) & 7;
      int sw  = c16 ^ (cv & 7);
      const ushort_t* src = Vb + (size_t)cv * NSP + n0 + sw * 8;
      ushort_t* dst = &VT[nb][(wid * 2048 + i * 1024) >> 1];
      __builtin_amdgcn_global_load_lds(
          (const __attribute__((address_space(1))) unsigned int*)src,
          (__attribute__((address_space(3))) unsigned int*)dst, 16, 0, 0);
    }
  };

  stageK(0, seg0); stageV(0, seg0);
  __syncthreads();

  int cur = 0;
  for (int t = 0; t < nts; ++t) {
    if (t + 1 < nts) {
      stageK(cur ^ 1, seg0 + (t + 1) * KB);
      stageV(cur ^ 1, seg0 + (t + 1) * KB);
    }

    // ---- QK^T ----
    f32x4 s[4];
#pragma unroll
    for (int kg = 0; kg < 4; ++kg) {
      int key = kg * 16 + l15;
      int sw  = g ^ ((key >> 1) & 3);
      bf16x8 kf = *(const bf16x8*)&KT[cur][key * CK + sw * 8];
      f32x4 z = {0.f, 0.f, 0.f, 0.f};
      s[kg] = __builtin_amdgcn_mfma_f32_16x16x32_bf16(qf, kf, z, 0, 0, 0);
    }

    // ---- exp (no max shift), accumulate denom, P -> per-wave LDS ----
#pragma unroll
    for (int r = 0; r < 4; ++r) {
      float ps = 0.f;
#pragma unroll
      for (int kg = 0; kg < 4; ++kg) {
        float p = __expf(s[kg][r]);
        ps += p;
        PL[wid][(4 * g + r) * 72 + kg * 16 + l15] = f2bf(p);
      }
      Ssum[r] += ps;
    }

    // ---- PV ----
#pragma unroll
    for (int ks = 0; ks < 2; ++ks) {
      bf16x8 pa = *(const bf16x8*)&PL[wid][l15 * 72 + ks * 32 + g * 8];
#pragma unroll
      for (int cg = 0; cg < 4; ++cg) {
        int cv   = cg * 16 + l15;
        int slot = ks * 4 + g;
        int sw   = slot ^ (cv & 7);
        bf16x8 vf = *(const bf16x8*)&VT[cur][cv * KB + sw * 8];
        acc[cg] = __builtin_amdgcn_mfma_f32_16x16x32_bf16(pa, vf, acc[cg], 0, 0, 0);
      }
    }

    __syncthreads();   // own-wave vmcnt drain => next tile staged; all waves synced
    cur ^= 1;
  }

  // ---- epilogue: reduce denom over 16-lane groups, write partials ----
#pragma unroll
  for (int r = 0; r < 4; ++r)
#pragma unroll
    for (int msk = 1; msk <= 8; msk <<= 1)
      Ssum[r] += __shfl_xor(Ssum[r], msk, 64);

  float* pb = pacc + ((size_t)(blockIdx.y * BATCH + b) * NSP) * CV;
#pragma unroll
  for (int r = 0; r < 4; ++r) {
    int q = q0 + wid * 16 + 4 * g + r;
#pragma unroll
    for (int cg = 0; cg < 4; ++cg)
      pb[(size_t)q * CV + cg * 16 + l15] = acc[cg][r];
    if (l15 == r) pS[((size_t)blockIdx.y * BATCH + b) * NSP + q] = Ssum[r];
  }
}

// ---------------------------------------------------------------------------
// Kernel 3: merge partials + f32 GEMM + residual.
// grid = B*(N/32), block 256. out = gamma*(W@ctx + Wb) + x
// ---------------------------------------------------------------------------
__global__ __launch_bounds__(256) void proj_kernel(
    const float* __restrict__ pacc,
    const float* __restrict__ pS,
    const float* __restrict__ Ww,
    const float* __restrict__ Wb,
    const float* __restrict__ gamma,
    const float* __restrict__ x,
    float* __restrict__ out,
    int nsplit) {
  __shared__ float Clds[32][68];
  __shared__ float Wlds[64][68];
  __shared__ float Sl[32];

  int tid = threadIdx.x;
  int b   = blockIdx.x / (NSP / 32);
  int n0  = (blockIdx.x % (NSP / 32)) * 32;

#pragma unroll
  for (int i = 0; i < 4; ++i) {            // W: 1024 float4s
    int e4 = tid + i * 256;
    int o = e4 >> 4, v4 = e4 & 15;
    *(float4_t*)&Wlds[o][v4 * 4] = ((const float4_t*)Ww)[e4];
  }
#pragma unroll
  for (int i = 0; i < 2; ++i) {            // merge: 512 float4s
    int e4 = tid + i * 256;
    int n = e4 >> 4, v4 = e4 & 15;
    float4_t ssum = {0.f, 0.f, 0.f, 0.f};
    for (int s = 0; s < nsplit; ++s) {
      float4_t t4 = ((const float4_t*)pacc)[((size_t)(s * BATCH + b) * NSP + n0 + n) * (CV / 4) + v4];
      ssum[0] += t4[0]; ssum[1] += t4[1]; ssum[2] += t4[2]; ssum[3] += t4[3];
    }
    *(float4_t*)&Clds[n][v4 * 4] = ssum;
  }
  if (tid < 32) {
    float ds = 0.f;
    for (int s = 0; s < nsplit; ++s)
      ds += pS[((size_t)s * BATCH + b) * NSP + n0 + tid];
    Sl[tid] = 1.f / ds;
  }
  __syncthreads();

  int n  = tid & 31;
  int og = tid >> 5;                       // 0..7, 8 outputs each
  float invn = Sl[n];
  float acc[8];
#pragma unroll
  for (int j = 0; j < 8; ++j) acc[j] = 0.f;

#pragma unroll
  for (int v4 = 0; v4 < 16; ++v4) {
    float4_t c4 = *(const float4_t*)&Clds[n][v4 * 4];
#pragma unroll
    for (int j = 0; j < 8; ++j) {
      float4_t w4 = *(const float4_t*)&Wlds[og * 8 + j][v4 * 4];
      acc[j] += w4[0] * c4[0] + w4[1] * c4[1] + w4[2] * c4[2] + w4[3] * c4[3];
    }
  }

  float gma = gamma[0];
#pragma unroll
  for (int j = 0; j < 8; ++j) {
    int o = og * 8 + j;
    size_t oi = ((size_t)b * COUT + o) * NSP + n0 + n;
    out[oi] = gma * (acc[j] * invn + Wb[o]) + x[oi];
  }
}

// ---------------------------------------------------------------------------
extern "C" void kernel_launch(void* const* d_in, const int* in_sizes, int n_in,
                              void* d_out, int out_size, void* d_ws, size_t ws_size,
                              hipStream_t stream) {
  const float* x        = (const float*)d_in[0];
  const float* key_w    = (const float*)d_in[1];
  const float* bn_gamma = (const float*)d_in[2];
  const float* bn_beta  = (const float*)d_in[3];
  const float* bn_mean  = (const float*)d_in[4];
  const float* bn_var   = (const float*)d_in[5];
  const float* value_w  = (const float*)d_in[6];
  const float* value_b  = (const float*)d_in[7];
  const float* W_w      = (const float*)d_in[8];
  const float* W_b      = (const float*)d_in[9];
  const float* gamma    = (const float*)d_in[10];
  float* out = (float*)d_out;

  ushort_t* KbT = (ushort_t*)d_ws;                       // [B][N][CK]  bf16
  ushort_t* Vbf = KbT + (size_t)BATCH * NSP * CK;        // [B][CV][N]  bf16
  float*    pacc = (float*)(Vbf + (size_t)BATCH * CV * NSP);
  size_t base_bytes = ((size_t)BATCH * NSP * (CK + CV)) * 2;

  int S = 8;
  while (S > 1 && base_bytes + (size_t)S * BATCH * NSP * (CV + 1) * 4 > ws_size)
    S >>= 1;
  float* pS = pacc + (size_t)S * BATCH * NSP * CV;

  kv_kernel<<<BATCH * (NSP / 32), 256, 0, stream>>>(
      x, key_w, bn_gamma, bn_beta, bn_mean, bn_var, value_w, value_b, KbT, Vbf);
  attn_kernel<<<dim3(BATCH * (NSP / 64), S), 256, 0, stream>>>(
      KbT, Vbf, pacc, pS, NSP / S);
  proj_kernel<<<BATCH * (NSP / 32), 256, 0, stream>>>(
      pacc, pS, W_w, W_b, gamma, x, out, S);
}